// Round 3
// baseline (1096.590 us; speedup 1.0000x reference)
//
#include <hip/hip_runtime.h>

// GNNML3 forward: 4x SpectConv(K=5) + relu, sum/max pool per graph, BN + FC + log_softmax.
// Key identity: (S_k x) W_k == S_k (x W_k) -> aggregate at input width, then dense GEMM.
// R3: two-phase CSR build (perm scatter writes 4B/edge; then sequential-write gather)
//     to kill the 197MB->38MB write amplification; aggregate edge-loop unrolled x4 for MLP.

#define Nn   50000
#define Ne   1600000
#define Gg   128
#define NEk  5
#define NINf 16
#define Hh   64
#define NCLSo 6
#define NB   196        // ceil((Nn+1)/256)

// ---------------- prep kernels ----------------

__global__ void k_pad_x(const float* __restrict__ x, float* __restrict__ h0) {
    int i = blockIdx.x * 256 + threadIdx.x;           // over Nn*64
    if (i >= Nn * 64) return;
    int n = i >> 6, f = i & 63;
    h0[i] = (f < NINf) ? x[n * NINf + f] : 0.f;
}

__global__ void k_pad_w1(const float* __restrict__ W1, float* __restrict__ W1p) {
    int i = blockIdx.x * 256 + threadIdx.x;           // over 5*64*64
    if (i >= NEk * 64 * 64) return;
    int h = i & 63, f = (i >> 6) & 63, k = i >> 12;
    W1p[i] = (f < NINf) ? W1[(k * NINf + f) * 64 + h] : 0.f;
}

__global__ void k_hist(const int* __restrict__ ei, int* __restrict__ deg) {
    int e = blockIdx.x * 256 + threadIdx.x;
    if (e >= Ne) return;
    atomicAdd(&deg[ei[Ne + e]], 1);                   // dst = ei[1][e]
}

// -------- 3-phase exclusive scan of deg[0..Nn] -> rowstart/cursor --------

__global__ void k_blocksum(const int* __restrict__ deg, int* __restrict__ bsum) {
    __shared__ int l[256];
    int t = threadIdx.x;
    int i = blockIdx.x * 256 + t;
    l[t] = (i < Nn) ? deg[i] : 0;
    __syncthreads();
    for (int off = 128; off > 0; off >>= 1) {
        if (t < off) l[t] += l[t + off];
        __syncthreads();
    }
    if (t == 0) bsum[blockIdx.x] = l[0];
}

__global__ void k_scanpart(const int* __restrict__ bsum, int* __restrict__ boff) {
    __shared__ int l[256];
    int t = threadIdx.x;
    int v = (t < NB) ? bsum[t] : 0;
    l[t] = v;
    __syncthreads();
    for (int off = 1; off < 256; off <<= 1) {
        int u = (t >= off) ? l[t - off] : 0;
        __syncthreads();
        l[t] += u;
        __syncthreads();
    }
    if (t < NB) boff[t] = l[t] - v;                   // exclusive
}

__global__ void k_scanfinal(const int* __restrict__ deg, const int* __restrict__ boff,
                            int* __restrict__ rowstart, int* __restrict__ cursor) {
    __shared__ int l[256];
    int t = threadIdx.x;
    int i = blockIdx.x * 256 + t;
    int v = (i < Nn) ? deg[i] : 0;
    l[t] = v;
    __syncthreads();
    for (int off = 1; off < 256; off <<= 1) {
        int u = (t >= off) ? l[t - off] : 0;
        __syncthreads();
        l[t] += u;
        __syncthreads();
    }
    if (i <= Nn) {
        int excl = boff[blockIdx.x] + l[t] - v;
        rowstart[i] = excl;
        cursor[i] = excl;
    }
}

// phase A: only a 4B perm entry goes to a random position (L3-resident, low write-amp)
__global__ void k_perm(const int* __restrict__ ei, int* __restrict__ cursor,
                       int* __restrict__ perm) {
    int e = blockIdx.x * 256 + threadIdx.x;
    if (e >= Ne) return;
    int d = ei[Ne + e];
    int pos = atomicAdd(&cursor[d], 1);
    perm[pos] = e;
}

// phase B: sequential writes, random (L2/L3-absorbed) reads
__global__ void k_gather_edges(const int* __restrict__ ei, const float* __restrict__ eattr,
                               const int* __restrict__ perm, int* __restrict__ srcs,
                               float4* __restrict__ attr4, float* __restrict__ attr1) {
    int pos = blockIdx.x * 256 + threadIdx.x;
    if (pos >= Ne) return;
    int e = perm[pos];
    srcs[pos] = ei[e];
    const float* a = eattr + (size_t)e * 5;
    attr4[pos] = make_float4(a[0], a[1], a[2], a[3]);
    attr1[pos] = a[4];
}

// batch is sorted (reference setup) -> segment bounds by boundary detection, no atomics
__global__ void k_bounds(const int* __restrict__ batch, int* __restrict__ sg,
                         int* __restrict__ eg) {
    int n = blockIdx.x * 256 + threadIdx.x;
    if (n >= Nn) return;
    int g = batch[n];
    if (n == 0) sg[g] = 0;
    else {
        int gp = batch[n - 1];
        if (gp != g) { sg[g] = n; eg[gp] = n; }
    }
    if (n == Nn - 1) eg[g] = Nn;
}

// ---------------- per-layer kernels ----------------

// one wave per node; lane = feature f (0..63); 5 register accumulators (spectral supports)
// edge loop unrolled x4: 4 independent hin gathers in flight per wave (latency hiding)
__global__ __launch_bounds__(256) void k_aggregate(
    const float* __restrict__ hin, const int* __restrict__ rowstart,
    const int* __restrict__ srcs, const float4* __restrict__ attr4,
    const float* __restrict__ attr1, float* __restrict__ agg) {
    int lane = threadIdx.x & 63;
    int node = __builtin_amdgcn_readfirstlane((int)(blockIdx.x * 4 + (threadIdx.x >> 6)));
    int beg = rowstart[node];
    int end = rowstart[node + 1];
    float acc0 = 0.f, acc1 = 0.f, acc2 = 0.f, acc3 = 0.f, acc4 = 0.f;
    int e = beg;
    for (; e + 4 <= end; e += 4) {
        int s0 = srcs[e], s1 = srcs[e + 1], s2 = srcs[e + 2], s3 = srcs[e + 3];
        float x0 = hin[(size_t)s0 * 64 + lane];
        float x1 = hin[(size_t)s1 * 64 + lane];
        float x2 = hin[(size_t)s2 * 64 + lane];
        float x3 = hin[(size_t)s3 * 64 + lane];
        float4 c0 = attr4[e],     c1 = attr4[e + 1];
        float4 c2 = attr4[e + 2], c3 = attr4[e + 3];
        float a0 = attr1[e],     a1 = attr1[e + 1];
        float a2 = attr1[e + 2], a3 = attr1[e + 3];
        acc0 = fmaf(c0.x, x0, acc0); acc1 = fmaf(c0.y, x0, acc1); acc2 = fmaf(c0.z, x0, acc2);
        acc3 = fmaf(c0.w, x0, acc3); acc4 = fmaf(a0,  x0, acc4);
        acc0 = fmaf(c1.x, x1, acc0); acc1 = fmaf(c1.y, x1, acc1); acc2 = fmaf(c1.z, x1, acc2);
        acc3 = fmaf(c1.w, x1, acc3); acc4 = fmaf(a1,  x1, acc4);
        acc0 = fmaf(c2.x, x2, acc0); acc1 = fmaf(c2.y, x2, acc1); acc2 = fmaf(c2.z, x2, acc2);
        acc3 = fmaf(c2.w, x2, acc3); acc4 = fmaf(a2,  x2, acc4);
        acc0 = fmaf(c3.x, x3, acc0); acc1 = fmaf(c3.y, x3, acc1); acc2 = fmaf(c3.z, x3, acc2);
        acc3 = fmaf(c3.w, x3, acc3); acc4 = fmaf(a3,  x3, acc4);
    }
    for (; e < end; ++e) {
        int s0 = srcs[e];
        float x0 = hin[(size_t)s0 * 64 + lane];
        float4 c = attr4[e];
        float c4 = attr1[e];
        acc0 = fmaf(c.x, x0, acc0); acc1 = fmaf(c.y, x0, acc1); acc2 = fmaf(c.z, x0, acc2);
        acc3 = fmaf(c.w, x0, acc3); acc4 = fmaf(c4, x0, acc4);
    }
    float* o = agg + (size_t)node * 320 + lane;
    o[0] = acc0; o[64] = acc1; o[128] = acc2; o[192] = acc3; o[256] = acc4;
}

// [64 nodes, 320] x [320, 64] + bias, relu. 256 threads, 4x4 register tile each.
__global__ __launch_bounds__(256) void k_transform(
    const float* __restrict__ A, const float* __restrict__ W,
    const float* __restrict__ bias, float* __restrict__ out) {
    int t = threadIdx.x;
    int tm = t >> 4, tn = t & 15;
    int n0 = blockIdx.x * 64 + tm * 4;
    int r[4];
#pragma unroll
    for (int j = 0; j < 4; ++j) { int rr = n0 + j; r[j] = rr < Nn ? rr : Nn - 1; }
    float acc[4][4];
#pragma unroll
    for (int j = 0; j < 4; ++j)
#pragma unroll
        for (int c = 0; c < 4; ++c) acc[j][c] = 0.f;
    const float* wp = W + tn * 4;
#pragma unroll 2
    for (int kk = 0; kk < 320; kk += 4) {
        float4 b0 = *(const float4*)(wp + (size_t)(kk + 0) * 64);
        float4 b1 = *(const float4*)(wp + (size_t)(kk + 1) * 64);
        float4 b2 = *(const float4*)(wp + (size_t)(kk + 2) * 64);
        float4 b3 = *(const float4*)(wp + (size_t)(kk + 3) * 64);
#pragma unroll
        for (int j = 0; j < 4; ++j) {
            float4 a = *(const float4*)(A + (size_t)r[j] * 320 + kk);
            acc[j][0] = fmaf(a.x, b0.x, fmaf(a.y, b1.x, fmaf(a.z, b2.x, fmaf(a.w, b3.x, acc[j][0]))));
            acc[j][1] = fmaf(a.x, b0.y, fmaf(a.y, b1.y, fmaf(a.z, b2.y, fmaf(a.w, b3.y, acc[j][1]))));
            acc[j][2] = fmaf(a.x, b0.z, fmaf(a.y, b1.z, fmaf(a.z, b2.z, fmaf(a.w, b3.z, acc[j][2]))));
            acc[j][3] = fmaf(a.x, b0.w, fmaf(a.y, b1.w, fmaf(a.z, b2.w, fmaf(a.w, b3.w, acc[j][3]))));
        }
    }
    float bb0 = bias[tn * 4 + 0], bb1 = bias[tn * 4 + 1];
    float bb2 = bias[tn * 4 + 2], bb3 = bias[tn * 4 + 3];
#pragma unroll
    for (int j = 0; j < 4; ++j) {
        int rr = n0 + j;
        if (rr < Nn) {
            float4 o;
            o.x = fmaxf(acc[j][0] + bb0, 0.f);
            o.y = fmaxf(acc[j][1] + bb1, 0.f);
            o.z = fmaxf(acc[j][2] + bb2, 0.f);
            o.w = fmaxf(acc[j][3] + bb3, 0.f);
            *(float4*)(out + (size_t)rr * 64 + tn * 4) = o;
        }
    }
}

// ---------------- pooling + head ----------------

__global__ __launch_bounds__(256) void k_pool(const float* __restrict__ h,
                                              const int* __restrict__ sg,
                                              const int* __restrict__ eg,
                                              float* __restrict__ pooled) {
    __shared__ float ls[256], lm[256];
    int g = blockIdx.x;
    int t = threadIdx.x, lane = t & 63, q = t >> 6;
    int s = sg[g], e = eg[g];
    float sum = 0.f, mx = 0.f;   // relu outputs are >= 0, so 0 is a valid max identity
    for (int n = s + q; n < e; n += 4) {
        float v = h[(size_t)n * 64 + lane];
        sum += v;
        mx = fmaxf(mx, v);
    }
    ls[t] = sum; lm[t] = mx;
    __syncthreads();
    if (q == 0) {
        float ss = ls[lane] + ls[64 + lane] + ls[128 + lane] + ls[192 + lane];
        float mm = fmaxf(fmaxf(lm[lane], lm[64 + lane]), fmaxf(lm[128 + lane], lm[192 + lane]));
        pooled[g * 128 + lane] = ss;
        pooled[g * 128 + 64 + lane] = mm;
    }
}

__global__ void k_head(const float* __restrict__ pooled, const float* __restrict__ gamma,
                       const float* __restrict__ beta, const float* __restrict__ mean,
                       const float* __restrict__ var, const float* __restrict__ fcw,
                       const float* __restrict__ fcb, float* __restrict__ out) {
    __shared__ float y[128];
    __shared__ float lg[8];
    int g = blockIdx.x, c = threadIdx.x;   // 128 threads
    float p = pooled[g * 128 + c];
    y[c] = (p - mean[c]) * rsqrtf(var[c] + 1e-5f) * gamma[c] + beta[c];
    __syncthreads();
    if (c < NCLSo) {
        float l = fcb[c];
        for (int i = 0; i < 128; ++i) l += y[i] * fcw[i * NCLSo + c];
        lg[c] = l;
    }
    __syncthreads();
    if (c == 0) {
        float m = lg[0];
        for (int j = 1; j < NCLSo; ++j) m = fmaxf(m, lg[j]);
        float se = 0.f;
        for (int j = 0; j < NCLSo; ++j) se += expf(lg[j] - m);
        float lse = m + logf(se);
        for (int j = 0; j < NCLSo; ++j) out[g * NCLSo + j] = lg[j] - lse;
    }
}

// ---------------- launch ----------------

static inline size_t rup(size_t x) { return (x + 255) & ~(size_t)255; }

extern "C" void kernel_launch(void* const* d_in, const int* in_sizes, int n_in,
                              void* d_out, int out_size, void* d_ws, size_t ws_size,
                              hipStream_t stream) {
    const float* x     = (const float*)d_in[0];
    const int*   ei    = (const int*)d_in[1];
    const float* eattr = (const float*)d_in[2];
    const int*   batch = (const int*)d_in[3];
    const float* W1    = (const float*)d_in[4];
    const float* b1    = (const float*)d_in[5];
    const float* W2    = (const float*)d_in[6];
    const float* b2    = (const float*)d_in[7];
    const float* W3    = (const float*)d_in[8];
    const float* b3    = (const float*)d_in[9];
    const float* W4    = (const float*)d_in[10];
    const float* b4    = (const float*)d_in[11];
    const float* gamma = (const float*)d_in[12];
    const float* beta  = (const float*)d_in[13];
    const float* mean  = (const float*)d_in[14];
    const float* var   = (const float*)d_in[15];
    const float* fcw   = (const float*)d_in[16];
    const float* fcb   = (const float*)d_in[17];
    float* out = (float*)d_out;

    char* p = (char*)d_ws;
    auto take = [&](size_t bytes) { char* r = p; p += rup(bytes); return r; };
    int*    deg      = (int*)take((size_t)(Nn + 1) * 4);
    int*    rowstart = (int*)take((size_t)(Nn + 1) * 4);
    int*    cursor   = (int*)take((size_t)(Nn + 1) * 4);
    int*    bsum     = (int*)take((size_t)NB * 4);
    int*    boff     = (int*)take((size_t)NB * 4);
    int*    perm     = (int*)take((size_t)Ne * 4);
    int*    srcs     = (int*)take((size_t)Ne * 4);
    float4* attr4    = (float4*)take((size_t)Ne * 16);
    float*  attr1    = (float*)take((size_t)Ne * 4);
    float*  hA       = (float*)take((size_t)Nn * 64 * 4);
    float*  hB       = (float*)take((size_t)Nn * 64 * 4);
    float*  agg      = (float*)take((size_t)Nn * 320 * 4);
    float*  W1p      = (float*)take((size_t)NEk * 64 * 64 * 4);
    float*  pooled   = (float*)take((size_t)Gg * 128 * 4);
    int*    sg       = (int*)take((size_t)Gg * 4);
    int*    eg       = (int*)take((size_t)Gg * 4);

    hipMemsetAsync(deg, 0, (size_t)(Nn + 1) * 4, stream);

    k_pad_x<<<(Nn * 64 + 255) / 256, 256, 0, stream>>>(x, hA);
    k_pad_w1<<<(NEk * 64 * 64 + 255) / 256, 256, 0, stream>>>(W1, W1p);
    k_hist<<<(Ne + 255) / 256, 256, 0, stream>>>(ei, deg);
    k_blocksum<<<NB, 256, 0, stream>>>(deg, bsum);
    k_scanpart<<<1, 256, 0, stream>>>(bsum, boff);
    k_scanfinal<<<NB, 256, 0, stream>>>(deg, boff, rowstart, cursor);
    k_perm<<<(Ne + 255) / 256, 256, 0, stream>>>(ei, cursor, perm);
    k_gather_edges<<<(Ne + 255) / 256, 256, 0, stream>>>(ei, eattr, perm, srcs, attr4, attr1);
    k_bounds<<<(Nn + 255) / 256, 256, 0, stream>>>(batch, sg, eg);

    const float* Ws[4] = { W1p, W2, W3, W4 };
    const float* bs[4] = { b1, b2, b3, b4 };
    float* cur = hA;
    float* nxt = hB;
    for (int L = 0; L < 4; ++L) {
        k_aggregate<<<Nn / 4, 256, 0, stream>>>(cur, rowstart, srcs, attr4, attr1, agg);
        k_transform<<<(Nn + 63) / 64, 256, 0, stream>>>(agg, Ws[L], bs[L], nxt);
        float* tmp = cur; cur = nxt; nxt = tmp;
    }

    k_pool<<<Gg, 256, 0, stream>>>(cur, sg, eg, pooled);
    k_head<<<Gg, 128, 0, stream>>>(pooled, gamma, beta, mean, var, fcw, fcb, out);
}

// Round 4
// 672.155 us; speedup vs baseline: 1.6315x; 1.6315x over previous
//
#include <hip/hip_runtime.h>

// GNNML3 forward. R4: bf16 hot path (h rows 128B, agg bf16, 16B edge records),
// rank-based deterministic placement (one atomic pass, one random-write pass).
// Random 4B and 24B writes cost the same (64B dirty sector/edge) -> pack records to 16B.

#define Nn   50000
#define Ne   1600000
#define Gg   128
#define NEk  5
#define NINf 16
#define NCLSo 6
#define NB   196        // ceil((Nn+1)/256)

__device__ __forceinline__ float2 bf2u(unsigned u) {
    return make_float2(__uint_as_float(u << 16), __uint_as_float(u & 0xffff0000u));
}
__device__ __forceinline__ unsigned f2bf(float a, float b) {
    unsigned ua = __float_as_uint(a), ub = __float_as_uint(b);
    ua += 0x7fffu + ((ua >> 16) & 1u);
    ub += 0x7fffu + ((ub >> 16) & 1u);
    return (ua >> 16) | (ub & 0xffff0000u);
}

// ---------------- prep kernels ----------------

// x [Nn][16] fp32 -> h0 [Nn][32] uint (bf16x2 pairs, features >=16 zero)
__global__ void k_pad_x(const float* __restrict__ x, unsigned* __restrict__ h0) {
    int i = blockIdx.x * 256 + threadIdx.x;           // over Nn*32
    if (i >= Nn * 32) return;
    int n = i >> 5, p = i & 31;
    int f0 = 2 * p;
    float v0 = (f0 < NINf) ? x[n * NINf + f0] : 0.f;
    float v1 = (f0 + 1 < NINf) ? x[n * NINf + f0 + 1] : 0.f;
    h0[i] = f2bf(v0, v1);
}

__global__ void k_pad_w1(const float* __restrict__ W1, float* __restrict__ W1p) {
    int i = blockIdx.x * 256 + threadIdx.x;           // over 5*64*64
    if (i >= NEk * 64 * 64) return;
    int h = i & 63, f = (i >> 6) & 63, k = i >> 12;
    W1p[i] = (f < NINf) ? W1[(k * NINf + f) * 64 + h] : 0.f;
}

// rank[e] = arrival index within dst bucket (coalesced write); deg histogram
__global__ void k_rank(const int* __restrict__ ei, int* __restrict__ deg,
                       int* __restrict__ rank) {
    int e = blockIdx.x * 256 + threadIdx.x;
    if (e >= Ne) return;
    rank[e] = atomicAdd(&deg[ei[Ne + e]], 1);
}

// -------- 3-phase exclusive scan of deg[0..Nn] -> rowstart --------

__global__ void k_blocksum(const int* __restrict__ deg, int* __restrict__ bsum) {
    __shared__ int l[256];
    int t = threadIdx.x;
    int i = blockIdx.x * 256 + t;
    l[t] = (i < Nn) ? deg[i] : 0;
    __syncthreads();
    for (int off = 128; off > 0; off >>= 1) {
        if (t < off) l[t] += l[t + off];
        __syncthreads();
    }
    if (t == 0) bsum[blockIdx.x] = l[0];
}

__global__ void k_scanpart(const int* __restrict__ bsum, int* __restrict__ boff) {
    __shared__ int l[256];
    int t = threadIdx.x;
    int v = (t < NB) ? bsum[t] : 0;
    l[t] = v;
    __syncthreads();
    for (int off = 1; off < 256; off <<= 1) {
        int u = (t >= off) ? l[t - off] : 0;
        __syncthreads();
        l[t] += u;
        __syncthreads();
    }
    if (t < NB) boff[t] = l[t] - v;                   // exclusive
}

__global__ void k_scanfinal(const int* __restrict__ deg, const int* __restrict__ boff,
                            int* __restrict__ rowstart) {
    __shared__ int l[256];
    int t = threadIdx.x;
    int i = blockIdx.x * 256 + t;
    int v = (i < Nn) ? deg[i] : 0;
    l[t] = v;
    __syncthreads();
    for (int off = 1; off < 256; off <<= 1) {
        int u = (t >= off) ? l[t - off] : 0;
        __syncthreads();
        l[t] += u;
        __syncthreads();
    }
    if (i <= Nn) rowstart[i] = boff[blockIdx.x] + l[t] - v;
}

// deterministic placement: 16B record {src, bf16 a0..a4} to pos (one random write/edge)
__global__ void k_place(const int* __restrict__ ei, const float* __restrict__ eattr,
                        const int* __restrict__ rowstart, const int* __restrict__ rank,
                        uint4* __restrict__ recs) {
    int e = blockIdx.x * 256 + threadIdx.x;
    if (e >= Ne) return;
    int d = ei[Ne + e];
    int pos = rowstart[d] + rank[e];
    const float* a = eattr + (size_t)e * 5;
    uint4 r;
    r.x = (unsigned)ei[e];
    r.y = f2bf(a[0], a[1]);
    r.z = f2bf(a[2], a[3]);
    r.w = f2bf(a[4], 0.f);
    recs[pos] = r;
}

// batch is sorted -> segment bounds by boundary detection
__global__ void k_bounds(const int* __restrict__ batch, int* __restrict__ sg,
                         int* __restrict__ eg) {
    int n = blockIdx.x * 256 + threadIdx.x;
    if (n >= Nn) return;
    int g = batch[n];
    if (n == 0) sg[g] = 0;
    else {
        int gp = batch[n - 1];
        if (gp != g) { sg[g] = n; eg[gp] = n; }
    }
    if (n == Nn - 1) eg[g] = Nn;
}

// ---------------- per-layer kernels ----------------

// one wave per node; half-wave (32 lanes) per edge, 2 features (bf16x2) per lane.
// unroll x4 -> 8 edges in flight per wave.
__global__ __launch_bounds__(256) void k_aggregate(
    const unsigned* __restrict__ hin, const int* __restrict__ rowstart,
    const uint4* __restrict__ recs, unsigned* __restrict__ agg) {
    int lane = threadIdx.x & 63;
    int l = lane & 31, half = lane >> 5;
    int node = __builtin_amdgcn_readfirstlane((int)(blockIdx.x * 4 + (threadIdx.x >> 6)));
    int beg = rowstart[node], end = rowstart[node + 1];
    float2 c0 = {0.f, 0.f}, c1 = c0, c2 = c0, c3 = c0, c4 = c0;
    int ee = beg;
#define EDGE(E) { \
    uint4 r = recs[(E)]; \
    unsigned hx = hin[(size_t)(int)r.x * 32 + l]; \
    float2 xv = bf2u(hx); \
    float2 A01 = bf2u(r.y), A23 = bf2u(r.z); \
    float a4v = __uint_as_float(r.w << 16); \
    c0.x = fmaf(A01.x, xv.x, c0.x); c0.y = fmaf(A01.x, xv.y, c0.y); \
    c1.x = fmaf(A01.y, xv.x, c1.x); c1.y = fmaf(A01.y, xv.y, c1.y); \
    c2.x = fmaf(A23.x, xv.x, c2.x); c2.y = fmaf(A23.x, xv.y, c2.y); \
    c3.x = fmaf(A23.y, xv.x, c3.x); c3.y = fmaf(A23.y, xv.y, c3.y); \
    c4.x = fmaf(a4v,  xv.x, c4.x); c4.y = fmaf(a4v,  xv.y, c4.y); }
    for (; ee + 8 <= end; ee += 8) {
        EDGE(ee + half) EDGE(ee + 2 + half) EDGE(ee + 4 + half) EDGE(ee + 6 + half)
    }
    for (; ee + 2 <= end; ee += 2) { EDGE(ee + half) }
    if (ee < end) { if (half == 0) { EDGE(ee) } }
#undef EDGE
    // fold half 1 into half 0 (xor-butterfly, both halves end with the total)
    c0.x += __shfl(c0.x, lane ^ 32); c0.y += __shfl(c0.y, lane ^ 32);
    c1.x += __shfl(c1.x, lane ^ 32); c1.y += __shfl(c1.y, lane ^ 32);
    c2.x += __shfl(c2.x, lane ^ 32); c2.y += __shfl(c2.y, lane ^ 32);
    c3.x += __shfl(c3.x, lane ^ 32); c3.y += __shfl(c3.y, lane ^ 32);
    c4.x += __shfl(c4.x, lane ^ 32); c4.y += __shfl(c4.y, lane ^ 32);
    if (half == 0) {
        unsigned* o = agg + (size_t)node * 160 + l;
        o[0]   = f2bf(c0.x, c0.y);
        o[32]  = f2bf(c1.x, c1.y);
        o[64]  = f2bf(c2.x, c2.y);
        o[96]  = f2bf(c3.x, c3.y);
        o[128] = f2bf(c4.x, c4.y);
    }
}

// [64 nodes, 320]bf16 x [320, 64]fp32 + bias, relu -> bf16. 4x4 tile/thread.
__global__ __launch_bounds__(256) void k_transform(
    const unsigned* __restrict__ A, const float* __restrict__ W,
    const float* __restrict__ bias, unsigned* __restrict__ outh) {
    int t = threadIdx.x;
    int tm = t >> 4, tn = t & 15;
    int n0 = blockIdx.x * 64 + tm * 4;
    int r[4];
#pragma unroll
    for (int j = 0; j < 4; ++j) { int rr = n0 + j; r[j] = rr < Nn ? rr : Nn - 1; }
    float acc[4][4];
#pragma unroll
    for (int j = 0; j < 4; ++j)
#pragma unroll
        for (int c = 0; c < 4; ++c) acc[j][c] = 0.f;
    const float* wp = W + tn * 4;
#pragma unroll 2
    for (int kk = 0; kk < 320; kk += 4) {
        float4 b0 = *(const float4*)(wp + (size_t)(kk + 0) * 64);
        float4 b1 = *(const float4*)(wp + (size_t)(kk + 1) * 64);
        float4 b2 = *(const float4*)(wp + (size_t)(kk + 2) * 64);
        float4 b3 = *(const float4*)(wp + (size_t)(kk + 3) * 64);
#pragma unroll
        for (int j = 0; j < 4; ++j) {
            uint2 u = *(const uint2*)(A + (size_t)r[j] * 160 + (kk >> 1));
            float2 f01 = bf2u(u.x), f23 = bf2u(u.y);
            acc[j][0] = fmaf(f01.x, b0.x, fmaf(f01.y, b1.x, fmaf(f23.x, b2.x, fmaf(f23.y, b3.x, acc[j][0]))));
            acc[j][1] = fmaf(f01.x, b0.y, fmaf(f01.y, b1.y, fmaf(f23.x, b2.y, fmaf(f23.y, b3.y, acc[j][1]))));
            acc[j][2] = fmaf(f01.x, b0.z, fmaf(f01.y, b1.z, fmaf(f23.x, b2.z, fmaf(f23.y, b3.z, acc[j][2]))));
            acc[j][3] = fmaf(f01.x, b0.w, fmaf(f01.y, b1.w, fmaf(f23.x, b2.w, fmaf(f23.y, b3.w, acc[j][3]))));
        }
    }
    float bb0 = bias[tn * 4 + 0], bb1 = bias[tn * 4 + 1];
    float bb2 = bias[tn * 4 + 2], bb3 = bias[tn * 4 + 3];
#pragma unroll
    for (int j = 0; j < 4; ++j) {
        int rr = n0 + j;
        if (rr < Nn) {
            uint2 o;
            o.x = f2bf(fmaxf(acc[j][0] + bb0, 0.f), fmaxf(acc[j][1] + bb1, 0.f));
            o.y = f2bf(fmaxf(acc[j][2] + bb2, 0.f), fmaxf(acc[j][3] + bb3, 0.f));
            *(uint2*)(outh + (size_t)rr * 32 + tn * 2) = o;
        }
    }
}

// ---------------- pooling + head ----------------

__global__ __launch_bounds__(256) void k_pool(const unsigned* __restrict__ h,
                                              const int* __restrict__ sg,
                                              const int* __restrict__ eg,
                                              float* __restrict__ pooled) {
    __shared__ float2 ls[256], lm[256];
    int g = blockIdx.x, t = threadIdx.x;
    int p = t & 31, q = t >> 5;                        // 32 feature-pairs x 8 node-strides
    int s = sg[g], e = eg[g];
    float2 sum = {0.f, 0.f}, mx = {0.f, 0.f};          // relu>=0 -> 0 valid max identity
    for (int n = s + q; n < e; n += 8) {
        float2 v = bf2u(h[(size_t)n * 32 + p]);
        sum.x += v.x; sum.y += v.y;
        mx.x = fmaxf(mx.x, v.x); mx.y = fmaxf(mx.y, v.y);
    }
    ls[t] = sum; lm[t] = mx;
    __syncthreads();
    if (t < 32) {
        float2 ss = ls[t], mm = lm[t];
        for (int i = 1; i < 8; ++i) {
            float2 a = ls[t + i * 32], b = lm[t + i * 32];
            ss.x += a.x; ss.y += a.y;
            mm.x = fmaxf(mm.x, b.x); mm.y = fmaxf(mm.y, b.y);
        }
        pooled[g * 128 + 2 * t]          = ss.x;
        pooled[g * 128 + 2 * t + 1]      = ss.y;
        pooled[g * 128 + 64 + 2 * t]     = mm.x;
        pooled[g * 128 + 64 + 2 * t + 1] = mm.y;
    }
}

__global__ void k_head(const float* __restrict__ pooled, const float* __restrict__ gamma,
                       const float* __restrict__ beta, const float* __restrict__ mean,
                       const float* __restrict__ var, const float* __restrict__ fcw,
                       const float* __restrict__ fcb, float* __restrict__ out) {
    __shared__ float y[128];
    __shared__ float lg[8];
    int g = blockIdx.x, c = threadIdx.x;   // 128 threads
    float p = pooled[g * 128 + c];
    y[c] = (p - mean[c]) * rsqrtf(var[c] + 1e-5f) * gamma[c] + beta[c];
    __syncthreads();
    if (c < NCLSo) {
        float l = fcb[c];
        for (int i = 0; i < 128; ++i) l += y[i] * fcw[i * NCLSo + c];
        lg[c] = l;
    }
    __syncthreads();
    if (c == 0) {
        float m = lg[0];
        for (int j = 1; j < NCLSo; ++j) m = fmaxf(m, lg[j]);
        float se = 0.f;
        for (int j = 0; j < NCLSo; ++j) se += expf(lg[j] - m);
        float lse = m + logf(se);
        for (int j = 0; j < NCLSo; ++j) out[g * NCLSo + j] = lg[j] - lse;
    }
}

// ---------------- launch ----------------

static inline size_t rup(size_t x) { return (x + 255) & ~(size_t)255; }

extern "C" void kernel_launch(void* const* d_in, const int* in_sizes, int n_in,
                              void* d_out, int out_size, void* d_ws, size_t ws_size,
                              hipStream_t stream) {
    const float* x     = (const float*)d_in[0];
    const int*   ei    = (const int*)d_in[1];
    const float* eattr = (const float*)d_in[2];
    const int*   batch = (const int*)d_in[3];
    const float* W1    = (const float*)d_in[4];
    const float* b1    = (const float*)d_in[5];
    const float* W2    = (const float*)d_in[6];
    const float* b2    = (const float*)d_in[7];
    const float* W3    = (const float*)d_in[8];
    const float* b3    = (const float*)d_in[9];
    const float* W4    = (const float*)d_in[10];
    const float* b4    = (const float*)d_in[11];
    const float* gamma = (const float*)d_in[12];
    const float* beta  = (const float*)d_in[13];
    const float* mean  = (const float*)d_in[14];
    const float* var   = (const float*)d_in[15];
    const float* fcw   = (const float*)d_in[16];
    const float* fcb   = (const float*)d_in[17];
    float* out = (float*)d_out;

    char* p = (char*)d_ws;
    auto take = [&](size_t bytes) { char* r = p; p += rup(bytes); return r; };
    int*      deg      = (int*)take((size_t)(Nn + 1) * 4);
    int*      rowstart = (int*)take((size_t)(Nn + 1) * 4);
    int*      bsum     = (int*)take((size_t)NB * 4);
    int*      boff     = (int*)take((size_t)NB * 4);
    int*      rank     = (int*)take((size_t)Ne * 4);
    uint4*    recs     = (uint4*)take((size_t)Ne * 16);
    unsigned* hA       = (unsigned*)take((size_t)Nn * 32 * 4);
    unsigned* hB       = (unsigned*)take((size_t)Nn * 32 * 4);
    unsigned* agg      = (unsigned*)take((size_t)Nn * 160 * 4);
    float*    W1p      = (float*)take((size_t)NEk * 64 * 64 * 4);
    float*    pooled   = (float*)take((size_t)Gg * 128 * 4);
    int*      sg       = (int*)take((size_t)Gg * 4);
    int*      eg       = (int*)take((size_t)Gg * 4);

    hipMemsetAsync(deg, 0, (size_t)(Nn + 1) * 4, stream);

    k_pad_x<<<(Nn * 32 + 255) / 256, 256, 0, stream>>>(x, hA);
    k_pad_w1<<<(NEk * 64 * 64 + 255) / 256, 256, 0, stream>>>(W1, W1p);
    k_rank<<<(Ne + 255) / 256, 256, 0, stream>>>(ei, deg, rank);
    k_blocksum<<<NB, 256, 0, stream>>>(deg, bsum);
    k_scanpart<<<1, 256, 0, stream>>>(bsum, boff);
    k_scanfinal<<<NB, 256, 0, stream>>>(deg, boff, rowstart);
    k_place<<<(Ne + 255) / 256, 256, 0, stream>>>(ei, eattr, rowstart, rank, recs);
    k_bounds<<<(Nn + 255) / 256, 256, 0, stream>>>(batch, sg, eg);

    const float* Ws[4] = { W1p, W2, W3, W4 };
    const float* bs[4] = { b1, b2, b3, b4 };
    unsigned* cur = hA;
    unsigned* nxt = hB;
    for (int L = 0; L < 4; ++L) {
        k_aggregate<<<Nn / 4, 256, 0, stream>>>(cur, rowstart, recs, agg);
        k_transform<<<(Nn + 63) / 64, 256, 0, stream>>>(agg, Ws[L], bs[L], nxt);
        unsigned* tmp = cur; cur = nxt; nxt = tmp;
    }

    k_pool<<<Gg, 256, 0, stream>>>(cur, sg, eg, pooled);
    k_head<<<Gg, 128, 0, stream>>>(pooled, gamma, beta, mean, var, fcw, fcb, out);
}

// Round 5
// 525.638 us; speedup vs baseline: 2.0862x; 1.2787x over previous
//
#include <hip/hip_runtime.h>

// GNNML3 forward. R5: k_transform -> MFMA GEMM (16x16x32 bf16) with split-precision
// W = Whi(bf16) + Wlo(bf16) accumulating in fp32 (keeps ~fp32 weight precision).
// A-tile (64x320 bf16) staged in LDS with +16B row pad (2-way conflicts = free;
// unpadded stride 640B would be 16-way). B pre-packed in MFMA B-fragment layout.

#define Nn   50000
#define Ne   1600000
#define Gg   128
#define NEk  5
#define NINf 16
#define NCLSo 6
#define NB   196        // ceil((Nn+1)/256)

using short8 = __attribute__((ext_vector_type(8))) short;
using f32x4  = __attribute__((ext_vector_type(4))) float;

__device__ __forceinline__ float2 bf2u(unsigned u) {
    return make_float2(__uint_as_float(u << 16), __uint_as_float(u & 0xffff0000u));
}
__device__ __forceinline__ unsigned f2bf(float a, float b) {
    unsigned ua = __float_as_uint(a), ub = __float_as_uint(b);
    ua += 0x7fffu + ((ua >> 16) & 1u);
    ub += 0x7fffu + ((ub >> 16) & 1u);
    return (ua >> 16) | (ub & 0xffff0000u);
}
__device__ __forceinline__ unsigned short f2bf1(float a) {
    unsigned ua = __float_as_uint(a);
    ua += 0x7fffu + ((ua >> 16) & 1u);
    return (unsigned short)(ua >> 16);
}

// ---------------- prep kernels ----------------

// x [Nn][16] fp32 -> h0 [Nn][32] uint (bf16x2 pairs, features >=16 zero)
__global__ void k_pad_x(const float* __restrict__ x, unsigned* __restrict__ h0) {
    int i = blockIdx.x * 256 + threadIdx.x;           // over Nn*32
    if (i >= Nn * 32) return;
    int n = i >> 5, p = i & 31;
    int f0 = 2 * p;
    float v0 = (f0 < NINf) ? x[n * NINf + f0] : 0.f;
    float v1 = (f0 + 1 < NINf) ? x[n * NINf + f0 + 1] : 0.f;
    h0[i] = f2bf(v0, v1);
}

__global__ void k_pad_w1(const float* __restrict__ W1, float* __restrict__ W1p) {
    int i = blockIdx.x * 256 + threadIdx.x;           // over 5*64*64
    if (i >= NEk * 64 * 64) return;
    int h = i & 63, f = (i >> 6) & 63, k = i >> 12;
    W1p[i] = (f < NINf) ? W1[(k * NINf + f) * 64 + h] : 0.f;
}

// pack W[320][64] fp32 into MFMA B-fragment layout, split hi/lo bf16.
// layout index: ((nt*10 + kstep)*64 + lane)*8 + j ; k = kstep*32 + (lane>>4)*8 + j,
// col = nt*16 + (lane&15).  20480 elements per layer.
__global__ void k_pack_b(const float* __restrict__ W, unsigned short* __restrict__ bhi,
                         unsigned short* __restrict__ blo) {
    int i = blockIdx.x * 256 + threadIdx.x;
    if (i >= 20480) return;
    int j = i & 7, lane = (i >> 3) & 63, t2 = i >> 9;   // t2 = nt*10+kstep, 0..39
    int nt = t2 / 10, kstep = t2 - nt * 10;
    int k = kstep * 32 + (lane >> 4) * 8 + j;
    int col = nt * 16 + (lane & 15);
    float v = W[k * 64 + col];
    unsigned short hi = f2bf1(v);
    float fhi = __uint_as_float(((unsigned)hi) << 16);
    bhi[i] = hi;
    blo[i] = f2bf1(v - fhi);
}

// rank[e] = arrival index within dst bucket (coalesced write); deg histogram
__global__ void k_rank(const int* __restrict__ ei, int* __restrict__ deg,
                       int* __restrict__ rank) {
    int e = blockIdx.x * 256 + threadIdx.x;
    if (e >= Ne) return;
    rank[e] = atomicAdd(&deg[ei[Ne + e]], 1);
}

// -------- 3-phase exclusive scan of deg[0..Nn] -> rowstart --------

__global__ void k_blocksum(const int* __restrict__ deg, int* __restrict__ bsum) {
    __shared__ int l[256];
    int t = threadIdx.x;
    int i = blockIdx.x * 256 + t;
    l[t] = (i < Nn) ? deg[i] : 0;
    __syncthreads();
    for (int off = 128; off > 0; off >>= 1) {
        if (t < off) l[t] += l[t + off];
        __syncthreads();
    }
    if (t == 0) bsum[blockIdx.x] = l[0];
}

__global__ void k_scanpart(const int* __restrict__ bsum, int* __restrict__ boff) {
    __shared__ int l[256];
    int t = threadIdx.x;
    int v = (t < NB) ? bsum[t] : 0;
    l[t] = v;
    __syncthreads();
    for (int off = 1; off < 256; off <<= 1) {
        int u = (t >= off) ? l[t - off] : 0;
        __syncthreads();
        l[t] += u;
        __syncthreads();
    }
    if (t < NB) boff[t] = l[t] - v;                   // exclusive
}

__global__ void k_scanfinal(const int* __restrict__ deg, const int* __restrict__ boff,
                            int* __restrict__ rowstart) {
    __shared__ int l[256];
    int t = threadIdx.x;
    int i = blockIdx.x * 256 + t;
    int v = (i < Nn) ? deg[i] : 0;
    l[t] = v;
    __syncthreads();
    for (int off = 1; off < 256; off <<= 1) {
        int u = (t >= off) ? l[t - off] : 0;
        __syncthreads();
        l[t] += u;
        __syncthreads();
    }
    if (i <= Nn) rowstart[i] = boff[blockIdx.x] + l[t] - v;
}

// deterministic placement: 16B record {src, bf16 a0..a4} to pos (one random write/edge)
__global__ void k_place(const int* __restrict__ ei, const float* __restrict__ eattr,
                        const int* __restrict__ rowstart, const int* __restrict__ rank,
                        uint4* __restrict__ recs) {
    int e = blockIdx.x * 256 + threadIdx.x;
    if (e >= Ne) return;
    int d = ei[Ne + e];
    int pos = rowstart[d] + rank[e];
    const float* a = eattr + (size_t)e * 5;
    uint4 r;
    r.x = (unsigned)ei[e];
    r.y = f2bf(a[0], a[1]);
    r.z = f2bf(a[2], a[3]);
    r.w = f2bf(a[4], 0.f);
    recs[pos] = r;
}

// batch is sorted -> segment bounds by boundary detection
__global__ void k_bounds(const int* __restrict__ batch, int* __restrict__ sg,
                         int* __restrict__ eg) {
    int n = blockIdx.x * 256 + threadIdx.x;
    if (n >= Nn) return;
    int g = batch[n];
    if (n == 0) sg[g] = 0;
    else {
        int gp = batch[n - 1];
        if (gp != g) { sg[g] = n; eg[gp] = n; }
    }
    if (n == Nn - 1) eg[g] = Nn;
}

// ---------------- per-layer kernels ----------------

// one wave per node; half-wave (32 lanes) per edge, 2 features (bf16x2) per lane.
// unroll x4 -> 8 edges in flight per wave.
__global__ __launch_bounds__(256) void k_aggregate(
    const unsigned* __restrict__ hin, const int* __restrict__ rowstart,
    const uint4* __restrict__ recs, unsigned* __restrict__ agg) {
    int lane = threadIdx.x & 63;
    int l = lane & 31, half = lane >> 5;
    int node = __builtin_amdgcn_readfirstlane((int)(blockIdx.x * 4 + (threadIdx.x >> 6)));
    int beg = rowstart[node], end = rowstart[node + 1];
    float2 c0 = {0.f, 0.f}, c1 = c0, c2 = c0, c3 = c0, c4 = c0;
    int ee = beg;
#define EDGE(E) { \
    uint4 r = recs[(E)]; \
    unsigned hx = hin[(size_t)(int)r.x * 32 + l]; \
    float2 xv = bf2u(hx); \
    float2 A01 = bf2u(r.y), A23 = bf2u(r.z); \
    float a4v = __uint_as_float(r.w << 16); \
    c0.x = fmaf(A01.x, xv.x, c0.x); c0.y = fmaf(A01.x, xv.y, c0.y); \
    c1.x = fmaf(A01.y, xv.x, c1.x); c1.y = fmaf(A01.y, xv.y, c1.y); \
    c2.x = fmaf(A23.x, xv.x, c2.x); c2.y = fmaf(A23.x, xv.y, c2.y); \
    c3.x = fmaf(A23.y, xv.x, c3.x); c3.y = fmaf(A23.y, xv.y, c3.y); \
    c4.x = fmaf(a4v,  xv.x, c4.x); c4.y = fmaf(a4v,  xv.y, c4.y); }
    for (; ee + 8 <= end; ee += 8) {
        EDGE(ee + half) EDGE(ee + 2 + half) EDGE(ee + 4 + half) EDGE(ee + 6 + half)
    }
    for (; ee + 2 <= end; ee += 2) { EDGE(ee + half) }
    if (ee < end) { if (half == 0) { EDGE(ee) } }
#undef EDGE
    // fold half 1 into half 0 (xor-butterfly, both halves end with the total)
    c0.x += __shfl(c0.x, lane ^ 32); c0.y += __shfl(c0.y, lane ^ 32);
    c1.x += __shfl(c1.x, lane ^ 32); c1.y += __shfl(c1.y, lane ^ 32);
    c2.x += __shfl(c2.x, lane ^ 32); c2.y += __shfl(c2.y, lane ^ 32);
    c3.x += __shfl(c3.x, lane ^ 32); c3.y += __shfl(c3.y, lane ^ 32);
    c4.x += __shfl(c4.x, lane ^ 32); c4.y += __shfl(c4.y, lane ^ 32);
    if (half == 0) {
        unsigned* o = agg + (size_t)node * 160 + l;
        o[0]   = f2bf(c0.x, c0.y);
        o[32]  = f2bf(c1.x, c1.y);
        o[64]  = f2bf(c2.x, c2.y);
        o[96]  = f2bf(c3.x, c3.y);
        o[128] = f2bf(c4.x, c4.y);
    }
}

// MFMA transform: [64 nodes x 320]bf16 x (Whi+Wlo)[320 x 64] + bias, relu -> bf16.
// Block: 256 thr = 4 waves; wave w owns rows w*16..w*16+15; A-tile in LDS, row
// stride 41 uint4 (656B: +16B pad). Per wave: 10 ksteps x 4 ntiles x 2 mfma.
#define SPAD 41
__global__ __launch_bounds__(256) void k_transform(
    const uint4* __restrict__ A, const unsigned short* __restrict__ bhi,
    const unsigned short* __restrict__ blo, const float* __restrict__ bias,
    unsigned* __restrict__ outh) {
    __shared__ uint4 smem[64 * SPAD];                  // 41984 B
    int t = threadIdx.x;
    int lane = t & 63, wave = t >> 6;
    int m = lane & 15, quad = lane >> 4;
    int blk = blockIdx.x;

    // stage A tile: 64 rows x 40 uint4, clamp node for tail block
#pragma unroll
    for (int it = 0; it < 10; ++it) {
        int v = t + it * 256;                          // 0..2559
        int row = v / 40, off = v - row * 40;
        int node = blk * 64 + row;
        if (node >= Nn) node = Nn - 1;
        smem[row * SPAD + off] = A[(size_t)node * 40 + off];
    }
    __syncthreads();

    f32x4 acc0 = {0.f, 0.f, 0.f, 0.f}, acc1 = acc0, acc2 = acc0, acc3 = acc0;
    const uint4* arow = smem + (wave * 16 + m) * SPAD + quad;
#pragma unroll 2
    for (int ks = 0; ks < 10; ++ks) {
        short8 a = *(const short8*)(arow + ks * 4);
        size_t bb = ((size_t)ks * 64 + lane) * 8;      // + nt*5120
        short8 h0 = *(const short8*)(bhi + bb);
        short8 l0 = *(const short8*)(blo + bb);
        acc0 = __builtin_amdgcn_mfma_f32_16x16x32_bf16(a, h0, acc0, 0, 0, 0);
        acc0 = __builtin_amdgcn_mfma_f32_16x16x32_bf16(a, l0, acc0, 0, 0, 0);
        short8 h1 = *(const short8*)(bhi + bb + 5120);
        short8 l1 = *(const short8*)(blo + bb + 5120);
        acc1 = __builtin_amdgcn_mfma_f32_16x16x32_bf16(a, h1, acc1, 0, 0, 0);
        acc1 = __builtin_amdgcn_mfma_f32_16x16x32_bf16(a, l1, acc1, 0, 0, 0);
        short8 h2 = *(const short8*)(bhi + bb + 10240);
        short8 l2 = *(const short8*)(blo + bb + 10240);
        acc2 = __builtin_amdgcn_mfma_f32_16x16x32_bf16(a, h2, acc2, 0, 0, 0);
        acc2 = __builtin_amdgcn_mfma_f32_16x16x32_bf16(a, l2, acc2, 0, 0, 0);
        short8 h3 = *(const short8*)(bhi + bb + 15360);
        short8 l3 = *(const short8*)(blo + bb + 15360);
        acc3 = __builtin_amdgcn_mfma_f32_16x16x32_bf16(a, h3, acc3, 0, 0, 0);
        acc3 = __builtin_amdgcn_mfma_f32_16x16x32_bf16(a, l3, acc3, 0, 0, 0);
    }
    __syncthreads();                                   // all waves done reading A

    // C layout (16x16x32): col=lane&15, row=quad*4+reg. Spill to LDS fp32 [wave][16][72].
    float* Cs = (float*)smem;
#pragma unroll
    for (int r = 0; r < 4; ++r) {
        int base = wave * 1152 + (quad * 4 + r) * 72 + m;
        Cs[base]      = acc0[r];
        Cs[base + 16] = acc1[r];
        Cs[base + 32] = acc2[r];
        Cs[base + 48] = acc3[r];
    }
    __syncthreads();

    // pack: thread -> row = t>>2, 8 consecutive bf16-pair slots
    int row = t >> 2, grp = t & 3;
    int node = blk * 64 + row;
    if (node < Nn) {
        const float* cr = Cs + (row >> 4) * 1152 + (row & 15) * 72;
        unsigned o[8];
#pragma unroll
        for (int j = 0; j < 8; ++j) {
            int pp = grp * 8 + j;
            float v0 = fmaxf(cr[2 * pp]     + bias[2 * pp],     0.f);
            float v1 = fmaxf(cr[2 * pp + 1] + bias[2 * pp + 1], 0.f);
            o[j] = f2bf(v0, v1);
        }
        uint4* dst = (uint4*)(outh + (size_t)node * 32 + grp * 8);
        dst[0] = make_uint4(o[0], o[1], o[2], o[3]);
        dst[1] = make_uint4(o[4], o[5], o[6], o[7]);
    }
}

// ---------------- pooling + head ----------------

__global__ __launch_bounds__(256) void k_pool(const unsigned* __restrict__ h,
                                              const int* __restrict__ sg,
                                              const int* __restrict__ eg,
                                              float* __restrict__ pooled) {
    __shared__ float2 ls[256], lm[256];
    int g = blockIdx.x, t = threadIdx.x;
    int p = t & 31, q = t >> 5;                        // 32 feature-pairs x 8 node-strides
    int s = sg[g], e = eg[g];
    float2 sum = {0.f, 0.f}, mx = {0.f, 0.f};          // relu>=0 -> 0 valid max identity
    for (int n = s + q; n < e; n += 8) {
        float2 v = bf2u(h[(size_t)n * 32 + p]);
        sum.x += v.x; sum.y += v.y;
        mx.x = fmaxf(mx.x, v.x); mx.y = fmaxf(mx.y, v.y);
    }
    ls[t] = sum; lm[t] = mx;
    __syncthreads();
    if (t < 32) {
        float2 ss = ls[t], mm = lm[t];
        for (int i = 1; i < 8; ++i) {
            float2 a = ls[t + i * 32], b = lm[t + i * 32];
            ss.x += a.x; ss.y += a.y;
            mm.x = fmaxf(mm.x, b.x); mm.y = fmaxf(mm.y, b.y);
        }
        pooled[g * 128 + 2 * t]          = ss.x;
        pooled[g * 128 + 2 * t + 1]      = ss.y;
        pooled[g * 128 + 64 + 2 * t]     = mm.x;
        pooled[g * 128 + 64 + 2 * t + 1] = mm.y;
    }
}

__global__ void k_head(const float* __restrict__ pooled, const float* __restrict__ gamma,
                       const float* __restrict__ beta, const float* __restrict__ mean,
                       const float* __restrict__ var, const float* __restrict__ fcw,
                       const float* __restrict__ fcb, float* __restrict__ out) {
    __shared__ float y[128];
    __shared__ float lg[8];
    int g = blockIdx.x, c = threadIdx.x;   // 128 threads
    float p = pooled[g * 128 + c];
    y[c] = (p - mean[c]) * rsqrtf(var[c] + 1e-5f) * gamma[c] + beta[c];
    __syncthreads();
    if (c < NCLSo) {
        float l = fcb[c];
        for (int i = 0; i < 128; ++i) l += y[i] * fcw[i * NCLSo + c];
        lg[c] = l;
    }
    __syncthreads();
    if (c == 0) {
        float m = lg[0];
        for (int j = 1; j < NCLSo; ++j) m = fmaxf(m, lg[j]);
        float se = 0.f;
        for (int j = 0; j < NCLSo; ++j) se += expf(lg[j] - m);
        float lse = m + logf(se);
        for (int j = 0; j < NCLSo; ++j) out[g * NCLSo + j] = lg[j] - lse;
    }
}

// ---------------- launch ----------------

static inline size_t rup(size_t x) { return (x + 255) & ~(size_t)255; }

extern "C" void kernel_launch(void* const* d_in, const int* in_sizes, int n_in,
                              void* d_out, int out_size, void* d_ws, size_t ws_size,
                              hipStream_t stream) {
    const float* x     = (const float*)d_in[0];
    const int*   ei    = (const int*)d_in[1];
    const float* eattr = (const float*)d_in[2];
    const int*   batch = (const int*)d_in[3];
    const float* W1    = (const float*)d_in[4];
    const float* b1    = (const float*)d_in[5];
    const float* W2    = (const float*)d_in[6];
    const float* b2    = (const float*)d_in[7];
    const float* W3    = (const float*)d_in[8];
    const float* b3    = (const float*)d_in[9];
    const float* W4    = (const float*)d_in[10];
    const float* b4    = (const float*)d_in[11];
    const float* gamma = (const float*)d_in[12];
    const float* beta  = (const float*)d_in[13];
    const float* mean  = (const float*)d_in[14];
    const float* var   = (const float*)d_in[15];
    const float* fcw   = (const float*)d_in[16];
    const float* fcb   = (const float*)d_in[17];
    float* out = (float*)d_out;

    char* p = (char*)d_ws;
    auto take = [&](size_t bytes) { char* r = p; p += rup(bytes); return r; };
    int*            deg      = (int*)take((size_t)(Nn + 1) * 4);
    int*            rowstart = (int*)take((size_t)(Nn + 1) * 4);
    int*            bsum     = (int*)take((size_t)NB * 4);
    int*            boff     = (int*)take((size_t)NB * 4);
    int*            rank     = (int*)take((size_t)Ne * 4);
    uint4*          recs     = (uint4*)take((size_t)Ne * 16);
    unsigned*       hA       = (unsigned*)take((size_t)Nn * 32 * 4);
    unsigned*       hB       = (unsigned*)take((size_t)Nn * 32 * 4);
    unsigned*       agg      = (unsigned*)take((size_t)Nn * 160 * 4);
    float*          W1p      = (float*)take((size_t)NEk * 64 * 64 * 4);
    unsigned short* bhiA     = (unsigned short*)take((size_t)4 * 20480 * 2);
    unsigned short* bloA     = (unsigned short*)take((size_t)4 * 20480 * 2);
    float*          pooled   = (float*)take((size_t)Gg * 128 * 4);
    int*            sg       = (int*)take((size_t)Gg * 4);
    int*            eg       = (int*)take((size_t)Gg * 4);

    hipMemsetAsync(deg, 0, (size_t)(Nn + 1) * 4, stream);

    k_pad_x<<<(Nn * 32 + 255) / 256, 256, 0, stream>>>(x, hA);
    k_pad_w1<<<(NEk * 64 * 64 + 255) / 256, 256, 0, stream>>>(W1, W1p);
    k_pack_b<<<80, 256, 0, stream>>>(W1p, bhiA,             bloA);
    k_pack_b<<<80, 256, 0, stream>>>(W2,  bhiA + 20480,     bloA + 20480);
    k_pack_b<<<80, 256, 0, stream>>>(W3,  bhiA + 2 * 20480, bloA + 2 * 20480);
    k_pack_b<<<80, 256, 0, stream>>>(W4,  bhiA + 3 * 20480, bloA + 3 * 20480);
    k_rank<<<(Ne + 255) / 256, 256, 0, stream>>>(ei, deg, rank);
    k_blocksum<<<NB, 256, 0, stream>>>(deg, bsum);
    k_scanpart<<<1, 256, 0, stream>>>(bsum, boff);
    k_scanfinal<<<NB, 256, 0, stream>>>(deg, boff, rowstart);
    k_place<<<(Ne + 255) / 256, 256, 0, stream>>>(ei, eattr, rowstart, rank, recs);
    k_bounds<<<(Nn + 255) / 256, 256, 0, stream>>>(batch, sg, eg);

    const float* bs[4] = { b1, b2, b3, b4 };
    unsigned* cur = hA;
    unsigned* nxt = hB;
    for (int L = 0; L < 4; ++L) {
        k_aggregate<<<Nn / 4, 256, 0, stream>>>(cur, rowstart, recs, agg);
        k_transform<<<(Nn + 63) / 64, 256, 0, stream>>>(
            (const uint4*)agg, bhiA + (size_t)L * 20480, bloA + (size_t)L * 20480,
            bs[L], nxt);
        unsigned* tmp = cur; cur = nxt; nxt = tmp;
    }

    k_pool<<<Gg, 256, 0, stream>>>(cur, sg, eg, pooled);
    k_head<<<Gg, 128, 0, stream>>>(pooled, gamma, beta, mean, var, fcw, fcb, out);
}